// Round 11
// baseline (296.246 us; speedup 1.0000x reference)
//
#include <hip/hip_runtime.h>
#include <hip/hip_bf16.h>

#define NTOK 16384
#define HID 7168
#define NEXP 256
#define TOPK 8

#define BT 64                  // tokens per block
#define BK 64                  // k per chunk
#define NCH (HID / BK)         // 112

typedef __bf16 bf16x8 __attribute__((ext_vector_type(8)));
typedef float  f32x16 __attribute__((ext_vector_type(16)));

typedef __attribute__((address_space(1))) const unsigned char ga_t;
typedef __attribute__((address_space(3))) unsigned char la_t;

// bf16 weights live in module global memory: no workspace dependency.
__device__ __align__(16) unsigned short g_wb[NEXP * HID];

// RTNE f32 -> bf16 bits
__device__ __forceinline__ unsigned int f2bfb(float x) {
    unsigned int u = __float_as_uint(x);
    return (u + 0x7fffu + ((u >> 16) & 1u)) >> 16;
}

// async 16B global -> LDS (dest = wave-uniform base + lane*16)
__device__ __forceinline__ void gll16(const void* g, void* l) {
    __builtin_amdgcn_global_load_lds((ga_t*)g, (la_t*)l, 16, 0, 0);
}

__device__ __forceinline__ bf16x8 cvt8(float4 p, float4 q) {
    union { bf16x8 v; __hip_bfloat162 h[4]; } c;
    c.h[0] = __float22bfloat162_rn(make_float2(p.x, p.y));
    c.h[1] = __float22bfloat162_rn(make_float2(p.z, p.w));
    c.h[2] = __float22bfloat162_rn(make_float2(q.x, q.y));
    c.h[3] = __float22bfloat162_rn(make_float2(q.z, q.w));
    return c.v;
}

// ---- pre-convert weight f32 -> bf16 into g_wb ----
__global__ void wconv(const float* __restrict__ wt) {
    const int i = blockIdx.x * 256 + threadIdx.x;      // over NEXP*HID/4 float4s
    const float4 v = ((const float4*)wt)[i];
    uint2 o;
    o.x = f2bfb(v.x) | (f2bfb(v.y) << 16);
    o.y = f2bfb(v.z) | (f2bfb(v.w) << 16);
    ((uint2*)g_wb)[i] = o;
}

// row_idx: row[t][k] = k*NTOK + t (chunk 2)
__global__ void moe_rows(float* __restrict__ ob) {
    const int q = blockIdx.x * 256 + threadIdx.x;
    ob[262144 + q] = (float)((q & 7) * NTOK + (q >> 3));
}

// LDS: 3 buffers x (A f32 16 KB + B bf16 32 KB) = 147456 B; epilogue aliases
// logits [64][257] f32 (65.8 KB) over the same region.
__global__ __launch_bounds__(512) void moe_gate_v11(
    const float* __restrict__ hs,
    float* __restrict__ ob)
{
    __shared__ __align__(16) char smem[147456];

    const int tid  = threadIdx.x;
    const int t0   = blockIdx.x * BT;
    const int lane = tid & 63;
    const int wv   = tid >> 6;        // 0..7
    const int wm   = wv >> 2;         // token half
    const int wn   = wv & 3;          // expert quarter

    // ---- staging source addresses (pre-swizzled so linear LDS dest = swizzled data) ----
    // A: per wave 2 insts; inst i covers token rows wv*8+i*4 .. +4 (256 B each)
    const char* aS[2];
    int aD[2];
    #pragma unroll
    for (int i = 0; i < 2; ++i) {
        const int r = wv * 8 + i * 4 + (lane >> 4);
        const int cs = (((lane & 15) << 4) ^ ((r & 15) << 4));
        aS[i] = (const char*)hs + ((size_t)(t0 + r) * HID) * 4 + cs;
        aD[i] = (wv * 8 + i * 4) * 256;
    }
    // B: per wave 4 insts; inst i covers expert rows wv*32+i*8 .. +8 (128 B each)
    const char* bS[4];
    int bD[4];
    #pragma unroll
    for (int i = 0; i < 4; ++i) {
        const int e = wv * 32 + i * 8 + (lane >> 3);
        const int cs = (((lane & 7) << 4) ^ (((lane >> 3) & 7) << 4));
        bS[i] = (const char*)g_wb + (size_t)e * HID * 2 + cs;
        bD[i] = 16384 + (wv * 32 + i * 8) * 128;
    }

    // ---- fragment read geometry ----
    const int khalf = lane >> 5;
    const int rowA  = wm * 32 + (lane & 31);
    const int aswz  = (rowA & 15) << 4;
    const int rowB  = wn * 64 + (lane & 31);
    const int bswz  = (rowB & 7) << 4;

    f32x16 acc0 = {};
    f32x16 acc1 = {};

    auto ISSUE = [&](int s, char* p) {
        #pragma unroll
        for (int i = 0; i < 2; ++i)
            gll16(aS[i] + (size_t)s * 256, p + aD[i]);
        #pragma unroll
        for (int i = 0; i < 4; ++i)
            gll16(bS[i] + (size_t)s * 128, p + bD[i]);
    };

    auto COMPUTE = [&](const char* p) {
        const char* A  = p;
        const char* Bp = p + 16384;
        #pragma unroll
        for (int kk = 0; kk < 4; ++kk) {
            const int ca = kk * 64 + khalf * 32;
            float4 a0 = *(const float4*)(A + rowA * 256 + ((ca     ) ^ aswz));
            float4 a1 = *(const float4*)(A + rowA * 256 + ((ca + 16) ^ aswz));
            bf16x8 a  = cvt8(a0, a1);
            const int cb = (kk * 32 + khalf * 16) ^ bswz;
            bf16x8 b0 = *(const bf16x8*)(Bp + rowB * 128 + cb);
            bf16x8 b1 = *(const bf16x8*)(Bp + (rowB + 32) * 128 + cb);
            acc0 = __builtin_amdgcn_mfma_f32_32x32x16_bf16(a, b0, acc0, 0, 0, 0);
            acc1 = __builtin_amdgcn_mfma_f32_32x32x16_bf16(a, b1, acc1, 0, 0, 0);
        }
    };

    char* p0 = smem;            // chunk s
    char* p1 = smem + 49152;    // chunk s+1 (in flight)
    char* p2 = smem + 98304;    // chunk s+2 (issued this iter)

    // ---- prologue: depth-2 ----
    ISSUE(0, p0);
    ISSUE(1, p1);

    // ---- main loop: counted vmcnt, never 0 ----
    for (int s = 0; s < NCH - 2; ++s) {
        ISSUE(s + 2, p2);                                   // 6 gll -> 18 outstanding
        asm volatile("s_waitcnt vmcnt(12)" ::: "memory");   // chunk s complete
        __builtin_amdgcn_s_barrier();
        __builtin_amdgcn_sched_barrier(0);
        COMPUTE(p0);
        __builtin_amdgcn_s_barrier();                       // reads of p0 done -> reusable
        __builtin_amdgcn_sched_barrier(0);
        char* t = p0; p0 = p1; p1 = p2; p2 = t;
    }
    // tail chunk NCH-2
    asm volatile("s_waitcnt vmcnt(6)" ::: "memory");
    __builtin_amdgcn_s_barrier();
    __builtin_amdgcn_sched_barrier(0);
    COMPUTE(p0);
    __builtin_amdgcn_s_barrier();
    __builtin_amdgcn_sched_barrier(0);
    { char* t = p0; p0 = p1; p1 = p2; p2 = t; }
    // tail chunk NCH-1
    asm volatile("s_waitcnt vmcnt(0)" ::: "memory");
    __builtin_amdgcn_s_barrier();
    __builtin_amdgcn_sched_barrier(0);
    COMPUTE(p0);
    __syncthreads();

    // ---- epilogue: dump logits to LDS [64][257] f32 ----
    float* ll = (float*)smem;
    {
        const int ec = wn * 64 + (lane & 31);
        const int rb = wm * 32 + 4 * (lane >> 5);
        #pragma unroll
        for (int r = 0; r < 16; ++r) {
            const int tok = rb + (r & 3) + 8 * (r >> 2);
            ll[tok * 257 + ec]      = acc0[r];
            ll[tok * 257 + ec + 32] = acc1[r];
        }
    }
    __syncthreads();

    if (tid < BT) {
        const float* lr = ll + tid * 257;
        float bv[TOPK]; int bi8[TOPK];
        #pragma unroll
        for (int k = 0; k < TOPK; ++k) { bv[k] = -1e30f; bi8[k] = 0; }
        for (int e = 0; e < NEXP; ++e) {
            const float v = lr[e];
            if (v > bv[TOPK - 1]) {
                int k = TOPK - 1;
                while (k > 0 && v > bv[k - 1]) {
                    bv[k] = bv[k - 1]; bi8[k] = bi8[k - 1]; --k;
                }
                bv[k] = v; bi8[k] = e;          // strict > : ties keep lower idx
            }
        }
        float ev[TOPK], ssum = 0.f;
        #pragma unroll
        for (int r = 0; r < TOPK; ++r) { ev[r] = expf(bv[r] - bv[0]); ssum += ev[r]; }
        const float inv = 1.0f / ssum;

        const int tg = t0 + tid;
        #pragma unroll
        for (int r = 0; r < TOPK; ++r) {
            ob[(size_t)tg * TOPK + r]          = (float)bi8[r];   // chunk 0: idx
            ob[131072 + (size_t)tg * TOPK + r] = ev[r] * inv;     // chunk 1: weight
        }
    }
}

extern "C" void kernel_launch(void* const* d_in, const int* in_sizes, int n_in,
                              void* d_out, int out_size, void* d_ws, size_t ws_size,
                              hipStream_t stream) {
    const float* hs = (const float*)d_in[0];   // [16384, 7168] f32
    const float* wt = (const float*)d_in[1];   // [256, 7168] f32
    float* ob = (float*)d_out;                 // f32[393216]: idx | weight | row

    wconv<<<dim3(NEXP * HID / 4 / 256), dim3(256), 0, stream>>>(wt);
    moe_gate_v11<<<dim3(NTOK / BT), dim3(512), 0, stream>>>(hs, ob);
    moe_rows<<<dim3(512), dim3(256), 0, stream>>>(ob);
}

// Round 12
// 248.334 us; speedup vs baseline: 1.1929x; 1.1929x over previous
//
#include <hip/hip_runtime.h>
#include <hip/hip_bf16.h>

#define NTOK 16384
#define HID 7168
#define NEXP 256
#define TOPK 8

#define BT 64                  // tokens per block
#define BK 128                 // k per phase
#define NPH (HID / BK)         // 56 phases

typedef __bf16 bf16x8 __attribute__((ext_vector_type(8)));
typedef float  f32x16 __attribute__((ext_vector_type(16)));

typedef __attribute__((address_space(1))) const unsigned char ga_t;
typedef __attribute__((address_space(3))) unsigned char la_t;

// Weights in MFMA-fragment-linear order:
// uint4 index tid = ((p*8 + g)*8 + ks)*64 + lane  holds
// B[e = g*32 + (lane&31)][k = p*128 + ks*16 + (lane>>5)*8 .. +8]  (8 bf16)
__device__ __align__(16) unsigned short g_wb[NEXP * HID];

// RTNE f32 -> bf16 bits
__device__ __forceinline__ unsigned int f2bfb(float x) {
    unsigned int u = __float_as_uint(x);
    return (u + 0x7fffu + ((u >> 16) & 1u)) >> 16;
}
__device__ __forceinline__ uint4 pk4(float4 p, float4 q) {
    uint4 u;
    u.x = f2bfb(p.x) | (f2bfb(p.y) << 16);
    u.y = f2bfb(p.z) | (f2bfb(p.w) << 16);
    u.z = f2bfb(q.x) | (f2bfb(q.y) << 16);
    u.w = f2bfb(q.z) | (f2bfb(q.w) << 16);
    return u;
}
__device__ __forceinline__ bf16x8 asbf8(uint4 u) {
    union { uint4 a; bf16x8 b; } c; c.a = u; return c.b;
}
__device__ __forceinline__ void gll16(const void* g, void* l) {
    __builtin_amdgcn_global_load_lds((ga_t*)g, (la_t*)l, 16, 0, 0);
}
__device__ __forceinline__ bf16x8 cvt8(float4 p, float4 q) {
    union { bf16x8 v; __hip_bfloat162 h[4]; } c;
    c.h[0] = __float22bfloat162_rn(make_float2(p.x, p.y));
    c.h[1] = __float22bfloat162_rn(make_float2(p.z, p.w));
    c.h[2] = __float22bfloat162_rn(make_float2(q.x, q.y));
    c.h[3] = __float22bfloat162_rn(make_float2(q.z, q.w));
    return c.v;
}

// ---- pre-convert + relayout weights into g_wb (fragment-linear) ----
__global__ void wconv_frag(const float* __restrict__ wt) {
    const int tid = blockIdx.x * 256 + threadIdx.x;   // 0 .. 229375
    const int l  = tid & 63;
    const int ks = (tid >> 6) & 7;
    const int g  = (tid >> 9) & 7;
    const int p  = tid >> 12;
    const int e  = g * 32 + (l & 31);
    const int kb = p * 128 + ks * 16 + ((l >> 5) << 3);
    const float4* s = (const float4*)(wt + (size_t)e * HID + kb);
    ((uint4*)g_wb)[tid] = pk4(s[0], s[1]);
}

// row_idx: row[t][k] = k*NTOK + t (chunk 2)
__global__ void moe_rows(float* __restrict__ ob) {
    const int q = blockIdx.x * 256 + threadIdx.x;
    ob[262144 + q] = (float)((q & 7) * NTOK + (q >> 3));
}

// LDS: A f32 dbuf 2 x 32 KB; epilogue aliases logits [64][257] f32 (65.8 KB)
__global__ __launch_bounds__(512) void moe_gate_v12(
    const float* __restrict__ hs,
    float* __restrict__ ob)
{
    __shared__ __align__(16) char smem[66560];
    char* const bufA0 = smem;
    char* const bufA1 = smem + 32768;

    const int tid  = threadIdx.x;
    const int t0   = blockIdx.x * BT;
    const int lane = tid & 63;
    const int wv   = tid >> 6;        // 0..7
    const int wm   = wv >> 2;         // token half
    const int wn   = wv & 3;          // expert quarter

    // ---- A gll staging: 32 KB/phase = 32 gll; 4 per wave; inst i covers 2 rows ----
    const char* aS[4];
    int aD[4];
    #pragma unroll
    for (int i = 0; i < 4; ++i) {
        const int r2 = (wv * 4 + i) * 2 + (lane >> 5);       // token row 0..63
        const int cs = ((lane & 31) * 16) ^ ((r2 & 31) << 4); // pre-swizzled source
        aS[i] = (const char*)hs + (size_t)(t0 + r2) * HID * 4 + cs;
        aD[i] = (wv * 4 + i) * 1024;
    }

    // ---- A fragment read geometry (512-B rows, 16-B-granule XOR swizzle) ----
    const int khalf = lane >> 5;
    const int rowA  = wm * 32 + (lane & 31);
    const int abase = rowA * 512;
    const int aswz  = (rowA & 31) << 4;

    // ---- B fragment-linear base: + p*65536 + (wn*2+c)*8192 + ks*1024 ----
    const char* const wbB = (const char*)g_wb + (size_t)(wn * 2) * 8192 + lane * 16;

    f32x16 acc0 = {};
    f32x16 acc1 = {};

    uint4 s0[16];   // B regs, phase-even (fully unrolled static indexing)
    uint4 s1[16];   // B regs, phase-odd

#define ISSUE_A(P, BUF)                                                       \
    do {                                                                      \
        _Pragma("unroll")                                                     \
        for (int i = 0; i < 4; ++i)                                           \
            gll16(aS[i] + (size_t)(P) * 512, (BUF) + aD[i]);                  \
        __builtin_amdgcn_sched_barrier(0);                                    \
    } while (0)

#define ISSUE_B(P, ARR)                                                       \
    do {                                                                      \
        const char* bp = wbB + (size_t)(P) * 65536;                           \
        _Pragma("unroll")                                                     \
        for (int c = 0; c < 2; ++c)                                           \
            _Pragma("unroll")                                                 \
            for (int ks = 0; ks < 8; ++ks)                                    \
                ARR[c * 8 + ks] = *(const uint4*)(bp + c * 8192 + ks * 1024); \
        __builtin_amdgcn_sched_barrier(0);                                    \
    } while (0)

#define COMPUTE(BUF, ARR)                                                     \
    do {                                                                      \
        _Pragma("unroll")                                                     \
        for (int ks = 0; ks < 8; ++ks) {                                      \
            const int o = ks * 64 + khalf * 32;                               \
            float4 a0 = *(const float4*)((BUF) + abase + ((o     ) ^ aswz));  \
            float4 a1 = *(const float4*)((BUF) + abase + ((o + 16) ^ aswz));  \
            bf16x8 a = cvt8(a0, a1);                                          \
            acc0 = __builtin_amdgcn_mfma_f32_32x32x16_bf16(a, asbf8(ARR[ks]),     acc0, 0, 0, 0); \
            acc1 = __builtin_amdgcn_mfma_f32_32x32x16_bf16(a, asbf8(ARR[8 + ks]), acc1, 0, 0, 0); \
        }                                                                     \
    } while (0)

// wait so that phase-p A gll + B loads are complete: newest 20 = B(p+1)16 + A(p+1)4
#define WAITBAR(VM)                                                           \
    do {                                                                      \
        asm volatile("s_waitcnt vmcnt(" #VM ")" ::: "memory");                \
        __builtin_amdgcn_sched_barrier(0);                                    \
        __builtin_amdgcn_s_barrier();                                         \
        __builtin_amdgcn_sched_barrier(0);                                    \
    } while (0)

#define ENDBAR()                                                              \
    do {                                                                      \
        __builtin_amdgcn_s_barrier();                                         \
        __builtin_amdgcn_sched_barrier(0);                                    \
    } while (0)

    // ---- prologue: B(0); A(0); A(1) ----
    ISSUE_B(0, s0);
    ISSUE_A(0, bufA0);
    ISSUE_A(1, bufA1);

    // ---- main loop: phases 0..53 (x2 unrolled), then peel 54, 55 ----
    for (int p = 0; p < 54; p += 2) {
        // even phase p: A in bufA0, B in s0
        ISSUE_B(p + 1, s1);
        WAITBAR(20);
        COMPUTE(bufA0, s0);
        ENDBAR();
        ISSUE_A(p + 2, bufA0);

        // odd phase p+1: A in bufA1, B in s1
        ISSUE_B(p + 2, s0);
        WAITBAR(20);
        COMPUTE(bufA1, s1);
        ENDBAR();
        if (p + 3 < NPH) ISSUE_A(p + 3, bufA1);
    }
    // phase 54 (bufA0, s0): issue B(55), no A(56)
    ISSUE_B(55, s1);
    WAITBAR(20);
    COMPUTE(bufA0, s0);
    ENDBAR();
    // phase 55 (bufA1, s1): nothing left to issue
    WAITBAR(0);
    COMPUTE(bufA1, s1);
    __syncthreads();

    // ---- epilogue: dump logits to LDS [64][257] f32 ----
    float* ll = (float*)smem;
    {
        const int ec = wn * 64 + (lane & 31);
        const int rb = wm * 32 + 4 * (lane >> 5);
        #pragma unroll
        for (int r = 0; r < 16; ++r) {
            const int tok = rb + (r & 3) + 8 * (r >> 2);
            ll[tok * 257 + ec]      = acc0[r];
            ll[tok * 257 + ec + 32] = acc1[r];
        }
    }
    __syncthreads();

    if (tid < BT) {
        const float* lr = ll + tid * 257;
        float bv[TOPK]; int bi8[TOPK];
        #pragma unroll
        for (int k = 0; k < TOPK; ++k) { bv[k] = -1e30f; bi8[k] = 0; }
        for (int e = 0; e < NEXP; ++e) {
            const float v = lr[e];
            if (v > bv[TOPK - 1]) {
                int k = TOPK - 1;
                while (k > 0 && v > bv[k - 1]) {
                    bv[k] = bv[k - 1]; bi8[k] = bi8[k - 1]; --k;
                }
                bv[k] = v; bi8[k] = e;          // strict > : ties keep lower idx
            }
        }
        float ev[TOPK], ssum = 0.f;
        #pragma unroll
        for (int r = 0; r < TOPK; ++r) { ev[r] = expf(bv[r] - bv[0]); ssum += ev[r]; }
        const float inv = 1.0f / ssum;

        const int tg = t0 + tid;
        #pragma unroll
        for (int r = 0; r < TOPK; ++r) {
            ob[(size_t)tg * TOPK + r]          = (float)bi8[r];   // chunk 0: idx
            ob[131072 + (size_t)tg * TOPK + r] = ev[r] * inv;     // chunk 1: weight
        }
    }
#undef ISSUE_A
#undef ISSUE_B
#undef COMPUTE
#undef WAITBAR
#undef ENDBAR
}

extern "C" void kernel_launch(void* const* d_in, const int* in_sizes, int n_in,
                              void* d_out, int out_size, void* d_ws, size_t ws_size,
                              hipStream_t stream) {
    const float* hs = (const float*)d_in[0];   // [16384, 7168] f32
    const float* wt = (const float*)d_in[1];   // [256, 7168] f32
    float* ob = (float*)d_out;                 // f32[393216]: idx | weight | row

    wconv_frag<<<dim3(NEXP * HID / 8 / 256), dim3(256), 0, stream>>>(wt);
    moe_gate_v12<<<dim3(NTOK / BT), dim3(512), 0, stream>>>(hs, ob);
    moe_rows<<<dim3(512), dim3(256), 0, stream>>>(ob);
}